// Round 3
// baseline (546.719 us; speedup 1.0000x reference)
//
#include <hip/hip_runtime.h>

#define S_LEN 2048
#define DMODEL 1024
#define NHEAD 16
#define DKEY 64

typedef __attribute__((ext_vector_type(8))) short bf16x8;
typedef __attribute__((ext_vector_type(4))) short short4v;
typedef __attribute__((ext_vector_type(4))) float f32x4;

__device__ __forceinline__ short f2bf(float f) {
  union { float f; unsigned u; } a; a.f = f;
  unsigned u = a.u;
  u += 0x7fff + ((u >> 16) & 1);   // round-to-nearest-even
  return (short)(u >> 16);
}

// ---------------------------------------------------------------------------
// Kernel 1: fused QKV projection + RoPE.  grid = (M/64, N/64, 3)
// z=0: Q (rope + 0.125 scale) -> [bh][s][dk]
// z=1: K (rope)               -> [bh][s][dk]
// z=2: V  (TRANSPOSED)        -> [bh][dk][s]   (direct PV B-frag loads in attn)
// ---------------------------------------------------------------------------
__global__ __launch_bounds__(256) void proj_qkv(
    const float* __restrict__ q, const float* __restrict__ k,
    const float* __restrict__ v,
    const float* __restrict__ Wq, const float* __restrict__ Wk,
    const float* __restrict__ Wv,
    const float* __restrict__ bq, const float* __restrict__ bk,
    const float* __restrict__ bv,
    const float* __restrict__ rope,
    short* __restrict__ Qw, short* __restrict__ Kw, short* __restrict__ Vw) {
  __shared__ short smem[5120];                    // 10 KB, aliased
  short (*As)[40] = (short(*)[40])smem;           // A tile 64x32, pad->40
  short (*Bt)[40] = (short(*)[40])(smem + 2560);  // W^T tile 64x32, pad->40
  short (*trans)[72] = (short(*)[72])smem;        // z==2 epilogue: 64x64, pad->72

  const int z = blockIdx.z;
  const float* X    = (z == 0) ? q  : (z == 1) ? k  : v;
  const float* W    = (z == 0) ? Wq : (z == 1) ? Wk : Wv;
  const float* bias = (z == 0) ? bq : (z == 1) ? bk : bv;

  const int m0 = blockIdx.x * 64;
  const int n0 = blockIdx.y * 64;
  const int t = threadIdx.x;
  const int lane = t & 63;
  const int w = t >> 6;
  const int quad = lane >> 4;
  const int l15 = lane & 15;
  const int wr = (w >> 1) * 32;   // wave row offset in 64x64 tile
  const int wc = (w & 1) * 32;    // wave col offset

  f32x4 acc[2][2] = {};

  const int ar = t >> 3, ac = (t & 7) * 4;    // A staging coords
  const int bkk = t >> 4, bn = (t & 15) * 4;  // B staging coords

  for (int kt = 0; kt < DMODEL; kt += 32) {
    __syncthreads();
#pragma unroll
    for (int p = 0; p < 2; ++p) {  // A: 64x32 f32 -> bf16
      const int r = p * 32 + ar;
      const float4 xv = *(const float4*)&X[(size_t)(m0 + r) * DMODEL + kt + ac];
      short4v s4b;
      s4b[0] = f2bf(xv.x); s4b[1] = f2bf(xv.y);
      s4b[2] = f2bf(xv.z); s4b[3] = f2bf(xv.w);
      *(short4v*)&As[r][ac] = s4b;
    }
#pragma unroll
    for (int p = 0; p < 2; ++p) {  // B: 32x64 f32 -> transposed bf16
      const int kk = p * 16 + bkk;
      const float4 wv = *(const float4*)&W[(size_t)(kt + kk) * DMODEL + n0 + bn];
      Bt[bn + 0][kk] = f2bf(wv.x);
      Bt[bn + 1][kk] = f2bf(wv.y);
      Bt[bn + 2][kk] = f2bf(wv.z);
      Bt[bn + 3][kk] = f2bf(wv.w);
    }
    __syncthreads();
    const bf16x8 a0 = *(const bf16x8*)&As[wr + l15][quad * 8];
    const bf16x8 a1 = *(const bf16x8*)&As[wr + 16 + l15][quad * 8];
    const bf16x8 b0 = *(const bf16x8*)&Bt[wc + l15][quad * 8];
    const bf16x8 b1 = *(const bf16x8*)&Bt[wc + 16 + l15][quad * 8];
    acc[0][0] = __builtin_amdgcn_mfma_f32_16x16x32_bf16(a0, b0, acc[0][0], 0, 0, 0);
    acc[0][1] = __builtin_amdgcn_mfma_f32_16x16x32_bf16(a0, b1, acc[0][1], 0, 0, 0);
    acc[1][0] = __builtin_amdgcn_mfma_f32_16x16x32_bf16(a1, b0, acc[1][0], 0, 0, 0);
    acc[1][1] = __builtin_amdgcn_mfma_f32_16x16x32_bf16(a1, b1, acc[1][1], 0, 0, 0);
  }

  const int b = m0 >> 11, s0 = m0 & 2047;
  const int h = n0 >> 6;

  if (z == 2) {
    // V: bias add, then 64x64 LDS transpose, store [bh][dk][s]
    __syncthreads();  // As/Bt still being read above; smem is aliased
#pragma unroll
    for (int ti = 0; ti < 2; ++ti)
#pragma unroll
      for (int tj = 0; tj < 2; ++tj) {
        const int dk = wc + tj * 16 + l15;
        const float bval = bias[n0 + dk];
#pragma unroll
        for (int reg = 0; reg < 4; ++reg) {
          const int sl = wr + ti * 16 + quad * 4 + reg;
          trans[dk][sl] = f2bf(acc[ti][tj][reg] + bval);
        }
      }
    __syncthreads();
    const int row = t >> 2;           // dk 0..63
    const int c0 = (t & 3) * 16;      // s_local 0..48
    const bf16x8 x0 = *(const bf16x8*)&trans[row][c0];
    const bf16x8 x1 = *(const bf16x8*)&trans[row][c0 + 8];
    short* dst = Vw + ((size_t)((b * NHEAD + h) * DKEY + row)) * S_LEN + s0 + c0;
    *(bf16x8*)&dst[0] = x0;
    *(bf16x8*)&dst[8] = x1;
    return;
  }

  // Q / K epilogue: bias, RoPE, scale (Q), store bf16 [bh][s][dk]
  short* outw = (z == 0) ? Qw : Kw;
#pragma unroll
  for (int ti = 0; ti < 2; ++ti) {
#pragma unroll
    for (int tj = 0; tj < 2; ++tj) {
      const int n = n0 + wc + tj * 16 + l15;
      const float bval = bias[n];
      const int dk = n & 63;
#pragma unroll
      for (int reg = 0; reg < 4; ++reg) {
        const int s = s0 + wr + ti * 16 + quad * 4 + reg;
        float val = acc[ti][tj][reg] + bval;
        // cos_i = rope[dk|1], sin_i = rope[dk&~1]; partner = x[dk^1] in lane^1
        const float cosv = rope[((size_t)b * S_LEN + s) * DKEY + (dk | 1)];
        const float sinv = rope[((size_t)b * S_LEN + s) * DKEY + (dk & ~1)];
        const float partner = __shfl_xor(val, 1);
        val = (dk & 1) ? (val * cosv + partner * sinv)
                       : (val * cosv - partner * sinv);
        if (z == 0) val *= 0.125f;  // 1/sqrt(KEY_SIZE)
        outw[((size_t)((b * NHEAD + h) * S_LEN + s)) * DKEY + dk] = f2bf(val);
      }
    }
  }
}

// ---------------------------------------------------------------------------
// Kernel 2: causal flash attention, S^T score layout.
// grid = (S/64, B*H), block = 256; one wave = 16 Q rows, no __syncthreads.
// S^T = K·Q^T (operand swap): a Q-row's 32 scores per j-step live in 8
// in-lane regs x 4 quads -> row softmax = in-register reduce + 2-level
// quad butterfly (combined (m,sum) online tree). m_i/l_i are per-lane
// scalars (row = l15); acc stays in standard C-layout (PV unchanged);
// alpha redistributed to (quad,r) rows via 4 parallel shuffles.
// ---------------------------------------------------------------------------
__global__ __launch_bounds__(256) void attn_kernel(
    const short* __restrict__ Qw, const short* __restrict__ Kw,
    const short* __restrict__ Vw, const float* __restrict__ v_mask,
    short* __restrict__ Ow) {
  __shared__ short Sb[4][16][40];  // per-wave P tile (C->A layout round-trip)

  const int t = threadIdx.x;
  const int w = t >> 6;
  const int lane = t & 63;
  const int quad = lane >> 4;
  const int l15 = lane & 15;
  const int bh = blockIdx.y;
  const int b = bh >> 4;
  const int qb = (gridDim.x - 1 - blockIdx.x) * 64 + w * 16;  // longest first

  // Q fragments: row = qb+l15, k contiguous (B-operand of S^T MFMA)
  const short* Qp = Qw + ((size_t)bh * S_LEN + qb + l15) * DKEY;
  const bf16x8 q_lo = *(const bf16x8*)(Qp + quad * 8);
  const bf16x8 q_hi = *(const bf16x8*)(Qp + 32 + quad * 8);

  float m_i = -1.0e30f, l_i = 0.f;   // per-lane: running max/sum of row qb+l15
  f32x4 acc[4] = {};

  const short* Kbase = Kw + (size_t)bh * S_LEN * DKEY;
  const short* Vbase = Vw + (size_t)bh * DKEY * S_LEN;  // transposed [dk][s]
  const float* vmb = v_mask + (size_t)b * S_LEN;

  auto loadK = [&](int j0, bf16x8& k0l, bf16x8& k0h, bf16x8& k1l,
                   bf16x8& k1h, float4& vm0, float4& vm1) {
    const short* Kp0 = Kbase + (size_t)(j0 + l15) * DKEY;
    k0l = *(const bf16x8*)(Kp0 + quad * 8);
    k0h = *(const bf16x8*)(Kp0 + 32 + quad * 8);
    const short* Kp1 = Kp0 + 16 * DKEY;
    k1l = *(const bf16x8*)(Kp1 + quad * 8);
    k1h = *(const bf16x8*)(Kp1 + 32 + quad * 8);
    vm0 = *(const float4*)&vmb[j0 + quad * 4];        // keys j0+4q+r
    vm1 = *(const float4*)&vmb[j0 + 16 + quad * 4];   // keys j0+16+4q+r
  };

  bf16x8 k0l, k0h, k1l, k1h;
  float4 vm0, vm1;
  loadK(0, k0l, k0h, k1l, k1h, vm0, vm1);

  const int qrow = qb + l15;              // this lane's Q row
  const int niter = (qb + 16 + 31) >> 5;  // ceil((qb+16)/32)
  for (int it = 0; it < niter; ++it) {
    const int j0 = it << 5;
    // S^T = K·Q^T: two 16(kcol)x16(qrow) tiles; operands swapped vs QK^T
    f32x4 s0v = {}, s1v = {};
    s0v = __builtin_amdgcn_mfma_f32_16x16x32_bf16(k0l, q_lo, s0v, 0, 0, 0);
    s0v = __builtin_amdgcn_mfma_f32_16x16x32_bf16(k0h, q_hi, s0v, 0, 0, 0);
    s1v = __builtin_amdgcn_mfma_f32_16x16x32_bf16(k1l, q_lo, s1v, 0, 0, 0);
    s1v = __builtin_amdgcn_mfma_f32_16x16x32_bf16(k1h, q_hi, s1v, 0, 0, 0);

    // V^T B-frags for this step (issued early; consumed after softmax)
    bf16x8 vb[4];
#pragma unroll
    for (int dt = 0; dt < 4; ++dt)
      vb[dt] = *(const bf16x8*)(Vbase + (size_t)(dt * 16 + l15) * S_LEN + j0 +
                                quad * 8);

    // prefetch next K + mask (clamped address -> branchless, in-bounds)
    const int jn = (it + 1 < niter) ? (j0 + 32) : 0;
    bf16x8 nk0l, nk0h, nk1l, nk1h;
    float4 nvm0, nvm1;
    loadK(jn, nk0l, nk0h, nk1l, nk1h, nvm0, nvm1);

    // mask: lane holds row qrow, keys kc0 = j0+4q+r and kc1 = kc0+16
#pragma unroll
    for (int r = 0; r < 4; ++r) {
      const int kc0 = j0 + quad * 4 + r;
      float x0 = s0v[r] + (vm0[r] - 1.0f) * 1.0e12f;
      float x1 = s1v[r] + (vm1[r] - 1.0f) * 1.0e12f;
      if (kc0 > qrow) x0 = -1.0e12f;
      if (kc0 + 16 > qrow) x1 = -1.0e12f;
      s0v[r] = x0; s1v[r] = x1;
    }
    // in-lane max over 8 scores
    float mloc = fmaxf(fmaxf(fmaxf(s0v[0], s0v[1]), fmaxf(s0v[2], s0v[3])),
                       fmaxf(fmaxf(s1v[0], s1v[1]), fmaxf(s1v[2], s1v[3])));
    // local exp + sum (masked entries: exp(-1e12 - mloc) flushes to 0;
    // fully-masked lane: mloc=-1e12 -> p=1 but pscale=exp(mloc-mn)=0 later)
    float p0[4], p1[4], sl = 0.f;
#pragma unroll
    for (int r = 0; r < 4; ++r) {
      p0[r] = __expf(s0v[r] - mloc);
      p1[r] = __expf(s1v[r] - mloc);
      sl += p0[r] + p1[r];
    }
    // combined (m, sum) butterfly over quads: xor 16, xor 32
    float mt = mloc, st = sl;
#pragma unroll
    for (int off = 16; off <= 32; off <<= 1) {
      const float mo = __shfl_xor(mt, off);
      const float so = __shfl_xor(st, off);
      const float mx = fmaxf(mt, mo);
      st = st * __expf(mt - mx) + so * __expf(mo - mx);
      mt = mx;
    }
    // online merge with running state (per-lane, row = qrow)
    const float mn = fmaxf(m_i, mt);
    const float alpha = __expf(m_i - mn);
    l_i = l_i * alpha + st * __expf(mt - mn);
    m_i = mn;
    const float pscale = __expf(mloc - mn);
    // alpha for acc rows quad*4+r (alpha is quad-uniform -> same-group lane)
    float af[4];
#pragma unroll
    for (int r = 0; r < 4; ++r)
      af[r] = __shfl(alpha, (lane & 48) + quad * 4 + r);
#pragma unroll
    for (int dt = 0; dt < 4; ++dt)
#pragma unroll
      for (int r = 0; r < 4; ++r) acc[dt][r] *= af[r];
    // P (S^T C-layout) -> A-layout via per-wave LDS: row=qrow-local=l15
#pragma unroll
    for (int r = 0; r < 4; ++r) {
      Sb[w][l15][quad * 4 + r] = f2bf(p0[r] * pscale);
      Sb[w][l15][16 + quad * 4 + r] = f2bf(p1[r] * pscale);
    }
    asm volatile("s_waitcnt lgkmcnt(0)" ::: "memory");
    const bf16x8 p_frag = *(const bf16x8*)&Sb[w][l15][quad * 8];
#pragma unroll
    for (int dt = 0; dt < 4; ++dt)
      acc[dt] = __builtin_amdgcn_mfma_f32_16x16x32_bf16(p_frag, vb[dt], acc[dt], 0, 0, 0);

    k0l = nk0l; k0h = nk0h; k1l = nk1l; k1h = nk1h;
    vm0 = nvm0; vm1 = nvm1;
  }
  // redistribute l to acc rows (quad*4+r), then O = acc/l -> [b][s][h*64+d]
  float lr[4];
#pragma unroll
  for (int r = 0; r < 4; ++r)
    lr[r] = __shfl(l_i, (lane & 48) + quad * 4 + r);
  const int h = bh & 15;
#pragma unroll
  for (int dt = 0; dt < 4; ++dt) {
#pragma unroll
    for (int r = 0; r < 4; ++r) {
      const int s = qb + quad * 4 + r;
      const float val = acc[dt][r] / lr[r];
      Ow[((size_t)(b * S_LEN + s)) * DMODEL + h * DKEY + dt * 16 + l15] = f2bf(val);
    }
  }
}

// ---------------------------------------------------------------------------
// Kernel 3: output projection  O(bf16, 4096x1024) @ Wo + bo -> f32 d_out
// ---------------------------------------------------------------------------
__global__ __launch_bounds__(256) void proj_out(
    const short* __restrict__ A, const float* __restrict__ W,
    const float* __restrict__ bias, float* __restrict__ out) {
  __shared__ short As[64][40];
  __shared__ short Bt[64][40];
  const int m0 = blockIdx.x * 64;
  const int n0 = blockIdx.y * 64;
  const int t = threadIdx.x;
  const int lane = t & 63;
  const int w = t >> 6;
  const int quad = lane >> 4;
  const int l15 = lane & 15;
  const int wr = (w >> 1) * 32;
  const int wc = (w & 1) * 32;
  f32x4 acc[2][2] = {};
  const int ar = t >> 2, ac = (t & 3) * 8;
  const int bkk = t >> 4, bn = (t & 15) * 4;

  for (int kt = 0; kt < DMODEL; kt += 32) {
    __syncthreads();
    *(bf16x8*)&As[ar][ac] = *(const bf16x8*)&A[(size_t)(m0 + ar) * DMODEL + kt + ac];
#pragma unroll
    for (int p = 0; p < 2; ++p) {
      const int kk = p * 16 + bkk;
      const float4 wv = *(const float4*)&W[(size_t)(kt + kk) * DMODEL + n0 + bn];
      Bt[bn + 0][kk] = f2bf(wv.x);
      Bt[bn + 1][kk] = f2bf(wv.y);
      Bt[bn + 2][kk] = f2bf(wv.z);
      Bt[bn + 3][kk] = f2bf(wv.w);
    }
    __syncthreads();
    const bf16x8 a0 = *(const bf16x8*)&As[wr + l15][quad * 8];
    const bf16x8 a1 = *(const bf16x8*)&As[wr + 16 + l15][quad * 8];
    const bf16x8 b0 = *(const bf16x8*)&Bt[wc + l15][quad * 8];
    const bf16x8 b1 = *(const bf16x8*)&Bt[wc + 16 + l15][quad * 8];
    acc[0][0] = __builtin_amdgcn_mfma_f32_16x16x32_bf16(a0, b0, acc[0][0], 0, 0, 0);
    acc[0][1] = __builtin_amdgcn_mfma_f32_16x16x32_bf16(a0, b1, acc[0][1], 0, 0, 0);
    acc[1][0] = __builtin_amdgcn_mfma_f32_16x16x32_bf16(a1, b0, acc[1][0], 0, 0, 0);
    acc[1][1] = __builtin_amdgcn_mfma_f32_16x16x32_bf16(a1, b1, acc[1][1], 0, 0, 0);
  }
#pragma unroll
  for (int ti = 0; ti < 2; ++ti)
#pragma unroll
    for (int tj = 0; tj < 2; ++tj) {
      const int n = n0 + wc + tj * 16 + l15;
      const float bval = bias[n];
#pragma unroll
      for (int r = 0; r < 4; ++r) {
        const int m = m0 + wr + ti * 16 + quad * 4 + r;
        out[(size_t)m * DMODEL + n] = acc[ti][tj][r] + bval;
      }
    }
}

// ---------------------------------------------------------------------------
extern "C" void kernel_launch(void* const* d_in, const int* in_sizes, int n_in,
                              void* d_out, int out_size, void* d_ws,
                              size_t ws_size, hipStream_t stream) {
  const float* q      = (const float*)d_in[0];
  const float* k      = (const float*)d_in[1];
  const float* v      = (const float*)d_in[2];
  const float* rope   = (const float*)d_in[3];
  // d_in[4] = a_bias: pure causal mask, recomputed from indices
  const float* v_mask = (const float*)d_in[5];
  const float* Wq = (const float*)d_in[6];
  const float* bq = (const float*)d_in[7];
  const float* Wk = (const float*)d_in[8];
  const float* bk = (const float*)d_in[9];
  const float* Wv = (const float*)d_in[10];
  const float* bv = (const float*)d_in[11];
  const float* Wo = (const float*)d_in[12];
  const float* bo = (const float*)d_in[13];
  float* out = (float*)d_out;

  short* ws = (short*)d_ws;
  short* Qw = ws;                       // [bh][s][dk] bf16, 8 MB
  short* Kw = ws + 4194304;             // [bh][s][dk] bf16, 8 MB
  short* Vw = ws + 8388608;             // [bh][dk][s] bf16 (transposed), 8 MB
  short* Ow = ws + 12582912;            // [b][s][dmodel] bf16, 8 MB

  proj_qkv<<<dim3(64, 16, 3), 256, 0, stream>>>(q, k, v, Wq, Wk, Wv, bq, bk, bv,
                                                rope, Qw, Kw, Vw);
  attn_kernel<<<dim3(32, 32), 256, 0, stream>>>(Qw, Kw, Vw, v_mask, Ow);
  proj_out<<<dim3(64, 16), 256, 0, stream>>>(Ow, Wo, bo, out);
}

// Round 4
// 508.798 us; speedup vs baseline: 1.0745x; 1.0745x over previous
//
#include <hip/hip_runtime.h>
#include <hip/hip_bf16.h>

#define S_LEN 2048
#define DMODEL 1024
#define NHEAD 16
#define DKEY 64

typedef __attribute__((ext_vector_type(8))) short bf16x8;
typedef __attribute__((ext_vector_type(4))) float f32x4;

__device__ __forceinline__ short f2bf(float f) {
  union { float f; unsigned u; } a; a.f = f;
  unsigned u = a.u;
  u += 0x7fff + ((u >> 16) & 1);   // RTNE
  return (short)(u >> 16);
}
__device__ __forceinline__ unsigned pk2bf(float a, float b) {
  union { __hip_bfloat162 h; unsigned u; } c;
  c.h = __float22bfloat162_rn(float2{a, b});
  return c.u;
}
__device__ __forceinline__ void gl_lds16(const void* g, void* l) {
  __builtin_amdgcn_global_load_lds(
      (const __attribute__((address_space(1))) unsigned int*)g,
      (__attribute__((address_space(3))) unsigned int*)l, 16, 0, 0);
}

// ---------------------------------------------------------------------------
// Kernel 0: weight transpose+convert. W[k][n] f32 -> Wt[n][k] bf16, 4 weights.
// grid (16,16,4), 256 thr, 64x64 tiles.
// ---------------------------------------------------------------------------
__global__ __launch_bounds__(256) void convert_w(
    const float* __restrict__ Wq, const float* __restrict__ Wk,
    const float* __restrict__ Wv, const float* __restrict__ Wo,
    short* __restrict__ Wt) {
  __shared__ short T[64][72];
  const int z = blockIdx.z;
  const float* W = (z == 0) ? Wq : (z == 1) ? Wk : (z == 2) ? Wv : Wo;
  short* dst = Wt + (size_t)z * 1048576;
  const int k0 = blockIdx.x * 64, n0 = blockIdx.y * 64;
  const int t = threadIdx.x;
#pragma unroll
  for (int p = 0; p < 4; ++p) {
    const int r = p * 16 + (t >> 4), c = (t & 15) * 4;
    const float4 wv = *(const float4*)&W[(size_t)(k0 + r) * DMODEL + n0 + c];
    T[c + 0][r] = f2bf(wv.x);
    T[c + 1][r] = f2bf(wv.y);
    T[c + 2][r] = f2bf(wv.z);
    T[c + 3][r] = f2bf(wv.w);
  }
  __syncthreads();
  const int rr = t >> 2, cc = (t & 3) * 16;
  const bf16x8 x0 = *(const bf16x8*)&T[rr][cc];
  const bf16x8 x1 = *(const bf16x8*)&T[rr][cc + 8];
  short* d = dst + (size_t)(n0 + rr) * DMODEL + k0 + cc;
  *(bf16x8*)&d[0] = x0;
  *(bf16x8*)&d[8] = x1;
}

// ---------------------------------------------------------------------------
// Kernel 1: QKV projection, m97-style 128x128 tile, BK=32, global_load_lds.
// A = X (fp32, XOR-chunk-swizzled LDS), B = Wt (bf16 [n][k]).
// grid (32, 8, 3): z=0 Q (RoPE+0.125 -> [bh][s][dk]), z=1 K (RoPE), z=2 V^T.
// ---------------------------------------------------------------------------
__global__ __launch_bounds__(256) void gemm_qkv(
    const float* __restrict__ q, const float* __restrict__ k,
    const float* __restrict__ v, const short* __restrict__ Wt,
    const float* __restrict__ bq, const float* __restrict__ bk,
    const float* __restrict__ bv, const float* __restrict__ rope,
    short* __restrict__ Qw, short* __restrict__ Kw, short* __restrict__ Vw) {
  __shared__ char smem[36864];                      // 36 KB
  float (*Asf)[32] = (float(*)[32])smem;            // 128x32 f32, 16 KB
  short (*Bs)[32] = (short(*)[32])(smem + 16384);   // 128x32 bf16, 8 KB

  const int z = blockIdx.z;
  const float* X    = (z == 0) ? q  : (z == 1) ? k  : v;
  const float* bias = (z == 0) ? bq : (z == 1) ? bk : bv;
  const short* Wz = Wt + (size_t)z * 1048576;

  const int m0 = blockIdx.x * 128, n0 = blockIdx.y * 128;
  const int t = threadIdx.x;
  const int lane = t & 63;
  const int w = t >> 6;
  const int quad = lane >> 4;
  const int l15 = lane & 15;
  const int wr = (w >> 1) * 64, wc = (w & 1) * 64;

  f32x4 acc[4][4] = {};

  // staging lane constants
  const int aRow = (lane >> 3);                 // 0..7 within 8-row issue
  const int aCh = (lane & 7) ^ aRow;            // XOR swizzle chunk
  const int bRow = (lane >> 2);                 // 0..15 within 16-row issue
  const int bCol = (lane & 3) * 8;
  const int xlo = ((lane & 7)) ;                // frag-read swizzle base (l15&7)

  for (int kt = 0; kt < DMODEL; kt += 32) {
    __syncthreads();
#pragma unroll
    for (int i = 0; i < 4; ++i) {               // A: 32 rows/wave, 8/issue
      const int row = w * 32 + i * 8 + aRow;
      gl_lds16(X + (size_t)(m0 + row) * DMODEL + kt + aCh * 4,
               &Asf[w * 32 + i * 8][0]);
    }
#pragma unroll
    for (int i = 0; i < 2; ++i) {               // B: 32 rows/wave, 16/issue
      const int row = w * 32 + i * 16 + bRow;
      gl_lds16(Wz + (size_t)(n0 + row) * DMODEL + kt + bCol,
               &Bs[w * 32 + i * 16][0]);
    }
    __syncthreads();
    bf16x8 bf[4];
#pragma unroll
    for (int nj = 0; nj < 4; ++nj)
      bf[nj] = *(const bf16x8*)&Bs[wc + nj * 16 + l15][quad * 8];
    const int x = l15 & 7;
#pragma unroll
    for (int mi = 0; mi < 4; ++mi) {
      const int row = wr + mi * 16 + l15;
      const f32x4 lo = *(const f32x4*)&Asf[row][((2 * quad) ^ x) * 4];
      const f32x4 hi = *(const f32x4*)&Asf[row][((2 * quad + 1) ^ x) * 4];
      union { unsigned u[4]; bf16x8 v; } af;
      af.u[0] = pk2bf(lo[0], lo[1]);
      af.u[1] = pk2bf(lo[2], lo[3]);
      af.u[2] = pk2bf(hi[0], hi[1]);
      af.u[3] = pk2bf(hi[2], hi[3]);
#pragma unroll
      for (int nj = 0; nj < 4; ++nj)
        acc[mi][nj] =
            __builtin_amdgcn_mfma_f32_16x16x32_bf16(af.v, bf[nj], acc[mi][nj], 0, 0, 0);
    }
  }

  const int b = (m0 + wr) >> 11;
  const int sbase = (m0 + wr) & 2047;

  if (z == 2) {
    // V epilogue: bias, per-wave 64x64 LDS transpose, store [bh][dk][s]
    __syncthreads();
    short (*tr)[72] = (short(*)[72])(smem + w * 9216);
    const int h = (n0 + wc) >> 6;
#pragma unroll
    for (int nj = 0; nj < 4; ++nj) {
      const float bval = bias[n0 + wc + nj * 16 + l15];
#pragma unroll
      for (int ti = 0; ti < 4; ++ti)
#pragma unroll
        for (int r = 0; r < 4; ++r)
          tr[nj * 16 + l15][ti * 16 + quad * 4 + r] = f2bf(acc[ti][nj][r] + bval);
    }
    asm volatile("s_waitcnt lgkmcnt(0)" ::: "memory");
    const int bh = b * NHEAD + h;
#pragma unroll
    for (int cc = 0; cc < 4; ++cc) {
      const int row = cc * 16 + (lane >> 2);
      const int c0 = (lane & 3) * 16;
      const bf16x8 x0 = *(const bf16x8*)&tr[row][c0];
      const bf16x8 x1 = *(const bf16x8*)&tr[row][c0 + 8];
      short* d = Vw + ((size_t)bh * DKEY + row) * S_LEN + sbase + c0;
      *(bf16x8*)&d[0] = x0;
      *(bf16x8*)&d[8] = x1;
    }
    return;
  }

  // Q/K epilogue: bias + RoPE (+0.125 for Q), store [bh][s][dk]
  short* outw = (z == 0) ? Qw : Kw;
#pragma unroll
  for (int nj = 0; nj < 4; ++nj) {
    const int n = n0 + wc + nj * 16 + l15;
    const float bval = bias[n];
    const int h = n >> 6, dk = n & 63;
    const int bh = b * NHEAD + h;
#pragma unroll
    for (int ti = 0; ti < 4; ++ti) {
#pragma unroll
      for (int r = 0; r < 4; ++r) {
        const int s = sbase + ti * 16 + quad * 4 + r;
        float val = acc[ti][nj][r] + bval;
        const float cosv = rope[((size_t)b * S_LEN + s) * DKEY + (dk | 1)];
        const float sinv = rope[((size_t)b * S_LEN + s) * DKEY + (dk & ~1)];
        const float partner = __shfl_xor(val, 1);
        val = (dk & 1) ? (val * cosv + partner * sinv)
                       : (val * cosv - partner * sinv);
        if (z == 0) val *= 0.125f;
        outw[((size_t)bh * S_LEN + s) * DKEY + dk] = f2bf(val);
      }
    }
  }
}

// ---------------------------------------------------------------------------
// Kernel 2: causal flash attention, S^T layout, j-step = 64 keys.
// grid (32, 32), 256 thr; one wave = 16 Q rows, no __syncthreads.
// ---------------------------------------------------------------------------
__global__ __launch_bounds__(256) void attn_kernel(
    const short* __restrict__ Qw, const short* __restrict__ Kw,
    const short* __restrict__ Vw, const float* __restrict__ v_mask,
    short* __restrict__ Ow) {
  __shared__ short Sb[4][16][72];  // per-wave P tile (64 keys + pad)

  const int t = threadIdx.x;
  const int w = t >> 6;
  const int lane = t & 63;
  const int quad = lane >> 4;
  const int l15 = lane & 15;
  const int bh = blockIdx.y;
  const int b = bh >> 4;
  const int qb = (gridDim.x - 1 - blockIdx.x) * 64 + w * 16;  // longest first

  const short* Qp = Qw + ((size_t)bh * S_LEN + qb + l15) * DKEY;
  const bf16x8 q_lo = *(const bf16x8*)(Qp + quad * 8);
  const bf16x8 q_hi = *(const bf16x8*)(Qp + 32 + quad * 8);

  float m_i = -1.0e30f, l_i = 0.f;  // per-lane, row = qb+l15
  f32x4 acc[4] = {};

  const short* Kbase = Kw + (size_t)bh * S_LEN * DKEY;
  const short* Vbase = Vw + (size_t)bh * DKEY * S_LEN;  // [dk][s]
  const float* vmb = v_mask + (size_t)b * S_LEN;

  const int qrow = qb + l15;
  const int niter = (qb + 16 + 63) >> 6;
  for (int it = 0; it < niter; ++it) {
    const int j0 = it << 6;
    // K fragments: 4 key-tiles of 16
    bf16x8 kl[4], kh[4];
    float4 vm[4];
#pragma unroll
    for (int jt = 0; jt < 4; ++jt) {
      const short* Kp = Kbase + (size_t)(j0 + jt * 16 + l15) * DKEY;
      kl[jt] = *(const bf16x8*)(Kp + quad * 8);
      kh[jt] = *(const bf16x8*)(Kp + 32 + quad * 8);
      vm[jt] = *(const float4*)&vmb[j0 + jt * 16 + quad * 4];
    }
    // S^T = K·Q^T
    f32x4 sv[4];
#pragma unroll
    for (int jt = 0; jt < 4; ++jt) {
      f32x4 s = {};
      s = __builtin_amdgcn_mfma_f32_16x16x32_bf16(kl[jt], q_lo, s, 0, 0, 0);
      s = __builtin_amdgcn_mfma_f32_16x16x32_bf16(kh[jt], q_hi, s, 0, 0, 0);
      sv[jt] = s;
    }
    // V^T frags for keys j0..j0+31 (issued early)
    bf16x8 vb0[4];
#pragma unroll
    for (int dt = 0; dt < 4; ++dt)
      vb0[dt] = *(const bf16x8*)(Vbase + (size_t)(dt * 16 + l15) * S_LEN + j0 +
                                 quad * 8);
    // mask: lane row = qrow, key = j0 + jt*16 + quad*4 + r
#pragma unroll
    for (int jt = 0; jt < 4; ++jt)
#pragma unroll
      for (int r = 0; r < 4; ++r) {
        const int kc = j0 + jt * 16 + quad * 4 + r;
        float xv = sv[jt][r] + (vm[jt][r] - 1.0f) * 1.0e12f;
        if (kc > qrow) xv = -1.0e12f;
        sv[jt][r] = xv;
      }
    // in-lane max over 16
    float mloc = -1.0e30f;
#pragma unroll
    for (int jt = 0; jt < 4; ++jt)
#pragma unroll
      for (int r = 0; r < 4; ++r) mloc = fmaxf(mloc, sv[jt][r]);
    // local exp + sum
    float p[4][4], sl = 0.f;
#pragma unroll
    for (int jt = 0; jt < 4; ++jt)
#pragma unroll
      for (int r = 0; r < 4; ++r) {
        p[jt][r] = __expf(sv[jt][r] - mloc);
        sl += p[jt][r];
      }
    // combined (m,sum) butterfly over quads
    float mt = mloc, st = sl;
#pragma unroll
    for (int off = 16; off <= 32; off <<= 1) {
      const float mo = __shfl_xor(mt, off);
      const float so = __shfl_xor(st, off);
      const float mx = fmaxf(mt, mo);
      st = st * __expf(mt - mx) + so * __expf(mo - mx);
      mt = mx;
    }
    const float mn = fmaxf(m_i, mt);
    const float alpha = __expf(m_i - mn);
    l_i = l_i * alpha + st * __expf(mt - mn);
    m_i = mn;
    const float pscale = __expf(mloc - mn);
    // alpha for acc rows quad*4+r
    float af[4];
#pragma unroll
    for (int r = 0; r < 4; ++r)
      af[r] = __shfl(alpha, (lane & 48) + quad * 4 + r);
#pragma unroll
    for (int dt = 0; dt < 4; ++dt)
#pragma unroll
      for (int r = 0; r < 4; ++r) acc[dt][r] *= af[r];
    // P -> A-layout via per-wave LDS (packed b64 writes)
#pragma unroll
    for (int jt = 0; jt < 4; ++jt) {
      uint2 pw;
      pw.x = pk2bf(p[jt][0] * pscale, p[jt][1] * pscale);
      pw.y = pk2bf(p[jt][2] * pscale, p[jt][3] * pscale);
      *(uint2*)&Sb[w][l15][jt * 16 + quad * 4] = pw;
    }
    // V^T frags for keys j0+32..j0+63
    bf16x8 vb1[4];
#pragma unroll
    for (int dt = 0; dt < 4; ++dt)
      vb1[dt] = *(const bf16x8*)(Vbase + (size_t)(dt * 16 + l15) * S_LEN + j0 +
                                 32 + quad * 8);
    asm volatile("s_waitcnt lgkmcnt(0)" ::: "memory");
    const bf16x8 pf0 = *(const bf16x8*)&Sb[w][l15][quad * 8];
    const bf16x8 pf1 = *(const bf16x8*)&Sb[w][l15][32 + quad * 8];
#pragma unroll
    for (int dt = 0; dt < 4; ++dt) {
      acc[dt] = __builtin_amdgcn_mfma_f32_16x16x32_bf16(pf0, vb0[dt], acc[dt], 0, 0, 0);
      acc[dt] = __builtin_amdgcn_mfma_f32_16x16x32_bf16(pf1, vb1[dt], acc[dt], 0, 0, 0);
    }
  }
  // redistribute l, O = acc/l -> [b][s][h*64+d]
  float lr[4];
#pragma unroll
  for (int r = 0; r < 4; ++r)
    lr[r] = __shfl(l_i, (lane & 48) + quad * 4 + r);
  const int h = bh & 15;
#pragma unroll
  for (int dt = 0; dt < 4; ++dt)
#pragma unroll
    for (int r = 0; r < 4; ++r) {
      const int s = qb + quad * 4 + r;
      Ow[((size_t)(b * S_LEN + s)) * DMODEL + h * DKEY + dt * 16 + l15] =
          f2bf(acc[dt][r] / lr[r]);
    }
}

// ---------------------------------------------------------------------------
// Kernel 3: output projection, m97-style, A = Ow bf16, B = Wt[3].
// grid (32, 8). fp32 out + bias.
// ---------------------------------------------------------------------------
__global__ __launch_bounds__(256) void gemm_out(
    const short* __restrict__ A, const short* __restrict__ Wz,
    const float* __restrict__ bias, float* __restrict__ out) {
  __shared__ char smem[16384];
  short (*As)[32] = (short(*)[32])smem;            // 128x32 bf16, 8 KB
  short (*Bs)[32] = (short(*)[32])(smem + 8192);   // 128x32 bf16, 8 KB

  const int m0 = blockIdx.x * 128, n0 = blockIdx.y * 128;
  const int t = threadIdx.x;
  const int lane = t & 63;
  const int w = t >> 6;
  const int quad = lane >> 4;
  const int l15 = lane & 15;
  const int wr = (w >> 1) * 64, wc = (w & 1) * 64;

  f32x4 acc[4][4] = {};
  const int sRow = (lane >> 2);
  const int sCol = (lane & 3) * 8;

  for (int kt = 0; kt < DMODEL; kt += 32) {
    __syncthreads();
#pragma unroll
    for (int i = 0; i < 2; ++i) {
      const int row = w * 32 + i * 16 + sRow;
      gl_lds16(A + (size_t)(m0 + row) * DMODEL + kt + sCol,
               &As[w * 32 + i * 16][0]);
      gl_lds16(Wz + (size_t)(n0 + row) * DMODEL + kt + sCol,
               &Bs[w * 32 + i * 16][0]);
    }
    __syncthreads();
    bf16x8 bf[4], af[4];
#pragma unroll
    for (int nj = 0; nj < 4; ++nj)
      bf[nj] = *(const bf16x8*)&Bs[wc + nj * 16 + l15][quad * 8];
#pragma unroll
    for (int mi = 0; mi < 4; ++mi)
      af[mi] = *(const bf16x8*)&As[wr + mi * 16 + l15][quad * 8];
#pragma unroll
    for (int mi = 0; mi < 4; ++mi)
#pragma unroll
      for (int nj = 0; nj < 4; ++nj)
        acc[mi][nj] =
            __builtin_amdgcn_mfma_f32_16x16x32_bf16(af[mi], bf[nj], acc[mi][nj], 0, 0, 0);
  }
#pragma unroll
  for (int nj = 0; nj < 4; ++nj) {
    const int n = n0 + wc + nj * 16 + l15;
    const float bval = bias[n];
#pragma unroll
    for (int ti = 0; ti < 4; ++ti)
#pragma unroll
      for (int r = 0; r < 4; ++r) {
        const int m = m0 + wr + ti * 16 + quad * 4 + r;
        out[(size_t)m * DMODEL + n] = acc[ti][nj][r] + bval;
      }
  }
}

// ---------------------------------------------------------------------------
extern "C" void kernel_launch(void* const* d_in, const int* in_sizes, int n_in,
                              void* d_out, int out_size, void* d_ws,
                              size_t ws_size, hipStream_t stream) {
  const float* q      = (const float*)d_in[0];
  const float* k      = (const float*)d_in[1];
  const float* v      = (const float*)d_in[2];
  const float* rope   = (const float*)d_in[3];
  const float* v_mask = (const float*)d_in[5];
  const float* Wq = (const float*)d_in[6];
  const float* bq = (const float*)d_in[7];
  const float* Wk = (const float*)d_in[8];
  const float* bk = (const float*)d_in[9];
  const float* Wv = (const float*)d_in[10];
  const float* bv = (const float*)d_in[11];
  const float* Wo = (const float*)d_in[12];
  const float* bo = (const float*)d_in[13];
  float* out = (float*)d_out;

  short* ws = (short*)d_ws;
  short* Qw = ws;                  // [bh][s][dk] bf16, 8 MB
  short* Kw = ws + 4194304;        // [bh][s][dk] bf16, 8 MB
  short* Vw = ws + 8388608;        // [bh][dk][s] bf16, 8 MB
  short* Ow = ws + 12582912;       // [b][s][dmodel] bf16, 8 MB
  short* Wt = ws + 16777216;       // 4x [n][k] bf16, 8 MB

  convert_w<<<dim3(16, 16, 4), 256, 0, stream>>>(Wq, Wk, Wv, Wo, Wt);
  gemm_qkv<<<dim3(32, 8, 3), 256, 0, stream>>>(q, k, v, Wt, bq, bk, bv, rope,
                                               Qw, Kw, Vw);
  attn_kernel<<<dim3(32, 32), 256, 0, stream>>>(Qw, Kw, Vw, v_mask, Ow);
  gemm_out<<<dim3(32, 8), 256, 0, stream>>>(Ow, Wt + 3145728, bo, out);
}

// Round 5
// 336.902 us; speedup vs baseline: 1.6228x; 1.5102x over previous
//
#include <hip/hip_runtime.h>
#include <hip/hip_bf16.h>

#define S_LEN 2048
#define DMODEL 1024
#define NHEAD 16
#define DKEY 64

typedef __attribute__((ext_vector_type(8))) short bf16x8;
typedef __attribute__((ext_vector_type(4))) float f32x4;

__device__ __forceinline__ short f2bf(float f) {
  union { float f; unsigned u; } a; a.f = f;
  unsigned u = a.u;
  u += 0x7fff + ((u >> 16) & 1);   // RTNE
  return (short)(u >> 16);
}
__device__ __forceinline__ unsigned pk2bf(float a, float b) {
  union { __hip_bfloat162 h; unsigned u; } c;
  c.h = __float22bfloat162_rn(float2{a, b});
  return c.u;
}
__device__ __forceinline__ void gl_lds16(const void* g, void* l) {
  __builtin_amdgcn_global_load_lds(
      (const __attribute__((address_space(1))) unsigned int*)g,
      (__attribute__((address_space(3))) unsigned int*)l, 16, 0, 0);
}

// ---------------------------------------------------------------------------
// Kernel 0: weight transpose+convert. W[k][n] f32 -> Wt[n][k] bf16, 4 weights.
// ---------------------------------------------------------------------------
__global__ __launch_bounds__(256) void convert_w(
    const float* __restrict__ Wq, const float* __restrict__ Wk,
    const float* __restrict__ Wv, const float* __restrict__ Wo,
    short* __restrict__ Wt) {
  __shared__ short T[64][72];
  const int z = blockIdx.z;
  const float* W = (z == 0) ? Wq : (z == 1) ? Wk : (z == 2) ? Wv : Wo;
  short* dst = Wt + (size_t)z * 1048576;
  const int k0 = blockIdx.x * 64, n0 = blockIdx.y * 64;
  const int t = threadIdx.x;
#pragma unroll
  for (int p = 0; p < 4; ++p) {
    const int r = p * 16 + (t >> 4), c = (t & 15) * 4;
    const float4 wv = *(const float4*)&W[(size_t)(k0 + r) * DMODEL + n0 + c];
    T[c + 0][r] = f2bf(wv.x);
    T[c + 1][r] = f2bf(wv.y);
    T[c + 2][r] = f2bf(wv.z);
    T[c + 3][r] = f2bf(wv.w);
  }
  __syncthreads();
  const int rr = t >> 2, cc = (t & 3) * 16;
  const bf16x8 x0 = *(const bf16x8*)&T[rr][cc];
  const bf16x8 x1 = *(const bf16x8*)&T[rr][cc + 8];
  short* d = dst + (size_t)(n0 + rr) * DMODEL + k0 + cc;
  *(bf16x8*)&d[0] = x0;
  *(bf16x8*)&d[8] = x1;
}

// ---------------------------------------------------------------------------
// Kernel 1: QKV projection, 128x128 tile, BK=32, global_load_lds.
// z=0 Q (RoPE+0.125 -> [bh][s][dk]), z=1 K (RoPE), z=2 V^T ([bh][dk][s]).
// ---------------------------------------------------------------------------
__global__ __launch_bounds__(256) void gemm_qkv(
    const float* __restrict__ q, const float* __restrict__ k,
    const float* __restrict__ v, const short* __restrict__ Wt,
    const float* __restrict__ bq, const float* __restrict__ bk,
    const float* __restrict__ bv, const float* __restrict__ rope,
    short* __restrict__ Qw, short* __restrict__ Kw, short* __restrict__ Vw) {
  __shared__ char smem[36864];                      // 36 KB
  float (*Asf)[32] = (float(*)[32])smem;            // 128x32 f32, 16 KB
  short (*Bs)[32] = (short(*)[32])(smem + 16384);   // 128x32 bf16, 8 KB

  const int z = blockIdx.z;
  const float* X    = (z == 0) ? q  : (z == 1) ? k  : v;
  const float* bias = (z == 0) ? bq : (z == 1) ? bk : bv;
  const short* Wz = Wt + (size_t)z * 1048576;

  const int m0 = blockIdx.x * 128, n0 = blockIdx.y * 128;
  const int t = threadIdx.x;
  const int lane = t & 63;
  const int w = t >> 6;
  const int quad = lane >> 4;
  const int l15 = lane & 15;
  const int wr = (w >> 1) * 64, wc = (w & 1) * 64;

  f32x4 acc[4][4] = {};

  const int aRow = (lane >> 3);
  const int aCh = (lane & 7) ^ aRow;
  const int bRow = (lane >> 2);
  const int bCol = (lane & 3) * 8;

  for (int kt = 0; kt < DMODEL; kt += 32) {
    __syncthreads();
#pragma unroll
    for (int i = 0; i < 4; ++i) {
      const int row = w * 32 + i * 8 + aRow;
      gl_lds16(X + (size_t)(m0 + row) * DMODEL + kt + aCh * 4,
               &Asf[w * 32 + i * 8][0]);
    }
#pragma unroll
    for (int i = 0; i < 2; ++i) {
      const int row = w * 32 + i * 16 + bRow;
      gl_lds16(Wz + (size_t)(n0 + row) * DMODEL + kt + bCol,
               &Bs[w * 32 + i * 16][0]);
    }
    __syncthreads();
    bf16x8 bf[4];
#pragma unroll
    for (int nj = 0; nj < 4; ++nj)
      bf[nj] = *(const bf16x8*)&Bs[wc + nj * 16 + l15][quad * 8];
    const int x = l15 & 7;
#pragma unroll
    for (int mi = 0; mi < 4; ++mi) {
      const int row = wr + mi * 16 + l15;
      const f32x4 lo = *(const f32x4*)&Asf[row][((2 * quad) ^ x) * 4];
      const f32x4 hi = *(const f32x4*)&Asf[row][((2 * quad + 1) ^ x) * 4];
      union { unsigned u[4]; bf16x8 v; } af;
      af.u[0] = pk2bf(lo[0], lo[1]);
      af.u[1] = pk2bf(lo[2], lo[3]);
      af.u[2] = pk2bf(hi[0], hi[1]);
      af.u[3] = pk2bf(hi[2], hi[3]);
#pragma unroll
      for (int nj = 0; nj < 4; ++nj)
        acc[mi][nj] =
            __builtin_amdgcn_mfma_f32_16x16x32_bf16(af.v, bf[nj], acc[mi][nj], 0, 0, 0);
    }
  }

  const int b = (m0 + wr) >> 11;
  const int sbase = (m0 + wr) & 2047;

  if (z == 2) {
    __syncthreads();
    short (*tr)[72] = (short(*)[72])(smem + w * 9216);
    const int h = (n0 + wc) >> 6;
#pragma unroll
    for (int nj = 0; nj < 4; ++nj) {
      const float bval = bias[n0 + wc + nj * 16 + l15];
#pragma unroll
      for (int ti = 0; ti < 4; ++ti)
#pragma unroll
        for (int r = 0; r < 4; ++r)
          tr[nj * 16 + l15][ti * 16 + quad * 4 + r] = f2bf(acc[ti][nj][r] + bval);
    }
    asm volatile("s_waitcnt lgkmcnt(0)" ::: "memory");
    const int bh = b * NHEAD + h;
#pragma unroll
    for (int cc = 0; cc < 4; ++cc) {
      const int row = cc * 16 + (lane >> 2);
      const int c0 = (lane & 3) * 16;
      const bf16x8 x0 = *(const bf16x8*)&tr[row][c0];
      const bf16x8 x1 = *(const bf16x8*)&tr[row][c0 + 8];
      short* d = Vw + ((size_t)bh * DKEY + row) * S_LEN + sbase + c0;
      *(bf16x8*)&d[0] = x0;
      *(bf16x8*)&d[8] = x1;
    }
    return;
  }

  short* outw = (z == 0) ? Qw : Kw;
#pragma unroll
  for (int nj = 0; nj < 4; ++nj) {
    const int n = n0 + wc + nj * 16 + l15;
    const float bval = bias[n];
    const int h = n >> 6, dk = n & 63;
    const int bh = b * NHEAD + h;
#pragma unroll
    for (int ti = 0; ti < 4; ++ti) {
#pragma unroll
      for (int r = 0; r < 4; ++r) {
        const int s = sbase + ti * 16 + quad * 4 + r;
        float val = acc[ti][nj][r] + bval;
        const float cosv = rope[((size_t)b * S_LEN + s) * DKEY + (dk | 1)];
        const float sinv = rope[((size_t)b * S_LEN + s) * DKEY + (dk & ~1)];
        const float partner = __shfl_xor(val, 1);
        val = (dk & 1) ? (val * cosv + partner * sinv)
                       : (val * cosv - partner * sinv);
        if (z == 0) val *= 0.125f;
        outw[((size_t)bh * S_LEN + s) * DKEY + dk] = f2bf(val);
      }
    }
  }
}

// ---------------------------------------------------------------------------
// Kernel 2: block-cooperative causal flash attention.
// grid (16, 32), 256 thr. Block x handles Q-chunks x and 31-x (uniform 33
// j-iterations per block). K/V^T staged in LDS per block (global_load_lds,
// XOR chunk swizzle, double-buffered, one barrier per j-step). Scores S^T,
// accumulate O^T = V^T·P^T so alpha & 1/l are per-lane scalars.
// ---------------------------------------------------------------------------
__global__ __launch_bounds__(256) void attn_kernel(
    const short* __restrict__ Qw, const short* __restrict__ Kw,
    const short* __restrict__ Vw, const float* __restrict__ v_mask,
    short* __restrict__ Ow) {
  __shared__ short Kt[2][64][64];  // keys x dk, 16 KB
  __shared__ short Vt[2][64][64];  // dk x keys, 16 KB
  __shared__ short Sb[4][16][72];  // per-wave P / O-transpose tile, 9 KB

  const int t = threadIdx.x;
  const int w = t >> 6;
  const int lane = t & 63;
  const int quad = lane >> 4;
  const int l15 = lane & 15;
  const int x8 = l15 & 7;
  const int bh = blockIdx.y;
  const int b = bh >> 4;
  const int h = bh & 15;

  const short* Kbase = Kw + (size_t)bh * S_LEN * DKEY;   // [s][dk]
  const short* Vbase = Vw + (size_t)bh * DKEY * S_LEN;   // [dk][s]
  const float* vmb = v_mask + (size_t)b * S_LEN;

  const int sRow = lane >> 3;           // 0..7 staging row within 8-row issue
  const int sCh = (lane & 7) ^ sRow;    // XOR-swizzled 16B chunk

  for (int pass = 0; pass < 2; ++pass) {
    const int c = pass ? (31 - (int)blockIdx.x) : (int)blockIdx.x;
    const int qb = c * 64;
    const int qrow = qb + w * 16 + l15;   // this lane's Q row (S^T col)

    const short* Qp = Qw + ((size_t)bh * S_LEN + qrow) * DKEY;
    const bf16x8 q_lo = *(const bf16x8*)(Qp + quad * 8);
    const bf16x8 q_hi = *(const bf16x8*)(Qp + 32 + quad * 8);

    float m_i = -1.0e30f, l_i = 0.f;   // per-lane, Q row = qrow
    f32x4 acc[4] = {};                 // O^T: d = dt*16+quad*4+r, q = l15

    const int niter = c + 1;
    __syncthreads();   // previous pass/iteration fully done with tiles
    // stage j=0 into buf 0
#pragma unroll
    for (int i = 0; i < 2; ++i) {
      const int kr = w * 16 + i * 8 + sRow;
      gl_lds16(Kbase + (size_t)kr * DKEY + sCh * 8, &Kt[0][w * 16 + i * 8][0]);
      gl_lds16(Vbase + (size_t)kr * S_LEN + 0 + sCh * 8, &Vt[0][w * 16 + i * 8][0]);
    }
    int cur = 0;
    for (int it = 0; it < niter; ++it) {
      const int j0 = it * 64;
      __syncthreads();   // drains vmcnt: buf[cur] staged; prev reads done
      if (it + 1 < niter) {
        const int jn = j0 + 64;
#pragma unroll
        for (int i = 0; i < 2; ++i) {
          const int kr = w * 16 + i * 8 + sRow;
          gl_lds16(Kbase + (size_t)(jn + kr) * DKEY + sCh * 8,
                   &Kt[cur ^ 1][w * 16 + i * 8][0]);
          gl_lds16(Vbase + (size_t)kr * S_LEN + jn + sCh * 8,
                   &Vt[cur ^ 1][w * 16 + i * 8][0]);
        }
      }
      // K A-frags (rows = keys, XOR-deswizzled chunks)
      bf16x8 ka[4][2];
#pragma unroll
      for (int kt = 0; kt < 4; ++kt) {
        ka[kt][0] = *(const bf16x8*)&Kt[cur][kt * 16 + l15][(quad ^ x8) * 8];
        ka[kt][1] = *(const bf16x8*)&Kt[cur][kt * 16 + l15][((4 + quad) ^ x8) * 8];
      }
      // S^T = K·Q^T
      f32x4 sv[4];
#pragma unroll
      for (int kt = 0; kt < 4; ++kt) {
        f32x4 s = {};
        s = __builtin_amdgcn_mfma_f32_16x16x32_bf16(ka[kt][0], q_lo, s, 0, 0, 0);
        s = __builtin_amdgcn_mfma_f32_16x16x32_bf16(ka[kt][1], q_hi, s, 0, 0, 0);
        sv[kt] = s;
      }
      // mask: key = j0 + kt*16 + quad*4 + r
#pragma unroll
      for (int kt = 0; kt < 4; ++kt) {
        const float4 vm = *(const float4*)&vmb[j0 + kt * 16 + quad * 4];
#pragma unroll
        for (int r = 0; r < 4; ++r) {
          const int kc = j0 + kt * 16 + quad * 4 + r;
          float xv = sv[kt][r] + (vm[r] - 1.0f) * 1.0e12f;
          if (kc > qrow) xv = -1.0e12f;
          sv[kt][r] = xv;
        }
      }
      // in-lane max over 16
      float mloc = -1.0e30f;
#pragma unroll
      for (int kt = 0; kt < 4; ++kt)
#pragma unroll
        for (int r = 0; r < 4; ++r) mloc = fmaxf(mloc, sv[kt][r]);
      // local exp + sum
      float p[4][4], sl = 0.f;
#pragma unroll
      for (int kt = 0; kt < 4; ++kt)
#pragma unroll
        for (int r = 0; r < 4; ++r) {
          p[kt][r] = __expf(sv[kt][r] - mloc);
          sl += p[kt][r];
        }
      // combined (m,sum) butterfly over quads (row spread: quad only)
      float mt = mloc, st = sl;
#pragma unroll
      for (int off = 16; off <= 32; off <<= 1) {
        const float mo = __shfl_xor(mt, off);
        const float so = __shfl_xor(st, off);
        const float mx = fmaxf(mt, mo);
        st = st * __expf(mt - mx) + so * __expf(mo - mx);
        mt = mx;
      }
      const float mn = fmaxf(m_i, mt);
      const float alpha = __expf(m_i - mn);
      l_i = l_i * alpha + st * __expf(mt - mn);
      m_i = mn;
      const float pscale = __expf(mloc - mn);
      // per-lane alpha scale of O^T accumulator (cols = q = l15)
#pragma unroll
      for (int dt = 0; dt < 4; ++dt)
#pragma unroll
        for (int r = 0; r < 4; ++r) acc[dt][r] *= alpha;
      // P store: Sb[q=l15][key], packed b64
#pragma unroll
      for (int kt = 0; kt < 4; ++kt) {
        uint2 pw;
        pw.x = pk2bf(p[kt][0] * pscale, p[kt][1] * pscale);
        pw.y = pk2bf(p[kt][2] * pscale, p[kt][3] * pscale);
        *(uint2*)&Sb[w][l15][kt * 16 + quad * 4] = pw;
      }
      asm volatile("s_waitcnt lgkmcnt(0)" ::: "memory");
      // P^T B-frags + V^T A-frags -> O^T accumulate
      const bf16x8 pf0 = *(const bf16x8*)&Sb[w][l15][quad * 8];
      const bf16x8 pf1 = *(const bf16x8*)&Sb[w][l15][32 + quad * 8];
#pragma unroll
      for (int dt = 0; dt < 4; ++dt) {
        const bf16x8 va0 =
            *(const bf16x8*)&Vt[cur][dt * 16 + l15][(quad ^ x8) * 8];
        acc[dt] = __builtin_amdgcn_mfma_f32_16x16x32_bf16(va0, pf0, acc[dt], 0, 0, 0);
        const bf16x8 va1 =
            *(const bf16x8*)&Vt[cur][dt * 16 + l15][((4 + quad) ^ x8) * 8];
        acc[dt] = __builtin_amdgcn_mfma_f32_16x16x32_bf16(va1, pf1, acc[dt], 0, 0, 0);
      }
      cur ^= 1;
    }
    // epilogue: O^T/l -> transpose via Sb -> Ow[b][s][h*64+d]
#pragma unroll
    for (int dt = 0; dt < 4; ++dt) {
      const float inv = 1.0f / l_i;
      uint2 ov;
      ov.x = pk2bf(acc[dt][0] * inv, acc[dt][1] * inv);
      ov.y = pk2bf(acc[dt][2] * inv, acc[dt][3] * inv);
      *(uint2*)&Sb[w][l15][dt * 16 + quad * 4] = ov;
    }
    asm volatile("s_waitcnt lgkmcnt(0)" ::: "memory");
    const int qr2 = lane >> 2;
    const int d0 = (lane & 3) * 16;
    const bf16x8 o0 = *(const bf16x8*)&Sb[w][qr2][d0];
    const bf16x8 o1 = *(const bf16x8*)&Sb[w][qr2][d0 + 8];
    short* dst =
        Ow + ((size_t)(b * S_LEN + qb + w * 16 + qr2)) * DMODEL + h * DKEY + d0;
    *(bf16x8*)&dst[0] = o0;
    *(bf16x8*)&dst[8] = o1;
  }
}

// ---------------------------------------------------------------------------
// Kernel 3: output projection, A = Ow bf16, B = Wt[3]. fp32 out + bias.
// ---------------------------------------------------------------------------
__global__ __launch_bounds__(256) void gemm_out(
    const short* __restrict__ A, const short* __restrict__ Wz,
    const float* __restrict__ bias, float* __restrict__ out) {
  __shared__ char smem[16384];
  short (*As)[32] = (short(*)[32])smem;
  short (*Bs)[32] = (short(*)[32])(smem + 8192);

  const int m0 = blockIdx.x * 128, n0 = blockIdx.y * 128;
  const int t = threadIdx.x;
  const int lane = t & 63;
  const int w = t >> 6;
  const int quad = lane >> 4;
  const int l15 = lane & 15;
  const int wr = (w >> 1) * 64, wc = (w & 1) * 64;

  f32x4 acc[4][4] = {};
  const int sRow = (lane >> 2);
  const int sCol = (lane & 3) * 8;

  for (int kt = 0; kt < DMODEL; kt += 32) {
    __syncthreads();
#pragma unroll
    for (int i = 0; i < 2; ++i) {
      const int row = w * 32 + i * 16 + sRow;
      gl_lds16(A + (size_t)(m0 + row) * DMODEL + kt + sCol,
               &As[w * 32 + i * 16][0]);
      gl_lds16(Wz + (size_t)(n0 + row) * DMODEL + kt + sCol,
               &Bs[w * 32 + i * 16][0]);
    }
    __syncthreads();
    bf16x8 bf[4], af[4];
#pragma unroll
    for (int nj = 0; nj < 4; ++nj)
      bf[nj] = *(const bf16x8*)&Bs[wc + nj * 16 + l15][quad * 8];
#pragma unroll
    for (int mi = 0; mi < 4; ++mi)
      af[mi] = *(const bf16x8*)&As[wr + mi * 16 + l15][quad * 8];
#pragma unroll
    for (int mi = 0; mi < 4; ++mi)
#pragma unroll
      for (int nj = 0; nj < 4; ++nj)
        acc[mi][nj] =
            __builtin_amdgcn_mfma_f32_16x16x32_bf16(af[mi], bf[nj], acc[mi][nj], 0, 0, 0);
  }
#pragma unroll
  for (int nj = 0; nj < 4; ++nj) {
    const int n = n0 + wc + nj * 16 + l15;
    const float bval = bias[n];
#pragma unroll
    for (int ti = 0; ti < 4; ++ti)
#pragma unroll
      for (int r = 0; r < 4; ++r) {
        const int m = m0 + wr + ti * 16 + quad * 4 + r;
        out[(size_t)m * DMODEL + n] = acc[ti][nj][r] + bval;
      }
  }
}

// ---------------------------------------------------------------------------
extern "C" void kernel_launch(void* const* d_in, const int* in_sizes, int n_in,
                              void* d_out, int out_size, void* d_ws,
                              size_t ws_size, hipStream_t stream) {
  const float* q      = (const float*)d_in[0];
  const float* k      = (const float*)d_in[1];
  const float* v      = (const float*)d_in[2];
  const float* rope   = (const float*)d_in[3];
  const float* v_mask = (const float*)d_in[5];
  const float* Wq = (const float*)d_in[6];
  const float* bq = (const float*)d_in[7];
  const float* Wk = (const float*)d_in[8];
  const float* bk = (const float*)d_in[9];
  const float* Wv = (const float*)d_in[10];
  const float* bv = (const float*)d_in[11];
  const float* Wo = (const float*)d_in[12];
  const float* bo = (const float*)d_in[13];
  float* out = (float*)d_out;

  short* ws = (short*)d_ws;
  short* Qw = ws;                  // [bh][s][dk] bf16, 8 MB
  short* Kw = ws + 4194304;        // [bh][s][dk] bf16, 8 MB
  short* Vw = ws + 8388608;        // [bh][dk][s] bf16, 8 MB
  short* Ow = ws + 12582912;       // [b][s][dmodel] bf16, 8 MB
  short* Wt = ws + 16777216;       // 4x [n][k] bf16, 8 MB

  convert_w<<<dim3(16, 16, 4), 256, 0, stream>>>(Wq, Wk, Wv, Wo, Wt);
  gemm_qkv<<<dim3(32, 8, 3), 256, 0, stream>>>(q, k, v, Wt, bq, bk, bv, rope,
                                               Qw, Kw, Vw);
  attn_kernel<<<dim3(16, 32), 256, 0, stream>>>(Qw, Kw, Vw, v_mask, Ow);
  gemm_out<<<dim3(32, 8), 256, 0, stream>>>(Ow, Wt + 3145728, bo, out);
}

// Round 6
// 286.144 us; speedup vs baseline: 1.9106x; 1.1774x over previous
//
#include <hip/hip_runtime.h>
#include <hip/hip_bf16.h>

#define S_LEN 2048
#define DMODEL 1024
#define NHEAD 16
#define DKEY 64

typedef __attribute__((ext_vector_type(8))) short bf16x8;
typedef __attribute__((ext_vector_type(4))) float f32x4;

__device__ __forceinline__ short f2bf(float f) {
  union { float f; unsigned u; } a; a.f = f;
  unsigned u = a.u;
  u += 0x7fff + ((u >> 16) & 1);   // RTNE
  return (short)(u >> 16);
}
__device__ __forceinline__ unsigned pk2bf(float a, float b) {
  union { __hip_bfloat162 h; unsigned u; } c;
  c.h = __float22bfloat162_rn(float2{a, b});
  return c.u;
}
__device__ __forceinline__ void gl_lds16(const void* g, void* l) {
  __builtin_amdgcn_global_load_lds(
      (const __attribute__((address_space(1))) unsigned int*)g,
      (__attribute__((address_space(3))) unsigned int*)l, 16, 0, 0);
}

// ---------------------------------------------------------------------------
// Kernel -1: X (q,k,v) fp32 -> bf16, elementwise. grid (4096, 3) x 256.
// ---------------------------------------------------------------------------
__global__ __launch_bounds__(256) void convert_x(
    const float* __restrict__ q, const float* __restrict__ k,
    const float* __restrict__ v, short* __restrict__ Xb) {
  const int z = blockIdx.y;
  const float* X = (z == 0) ? q : (z == 1) ? k : v;
  short* dst = Xb + (size_t)z * 4194304;
  const int i = (blockIdx.x * 256 + threadIdx.x) * 4;
  const float4 xv = *(const float4*)&X[i];
  uint2 o;
  o.x = pk2bf(xv.x, xv.y);
  o.y = pk2bf(xv.z, xv.w);
  *(uint2*)&dst[i] = o;
}

// ---------------------------------------------------------------------------
// Kernel 0: weight transpose+convert. W[k][n] f32 -> Wt[n][k] bf16, 4 weights.
// ---------------------------------------------------------------------------
__global__ __launch_bounds__(256) void convert_w(
    const float* __restrict__ Wq, const float* __restrict__ Wk,
    const float* __restrict__ Wv, const float* __restrict__ Wo,
    short* __restrict__ Wt) {
  __shared__ short T[64][72];
  const int z = blockIdx.z;
  const float* W = (z == 0) ? Wq : (z == 1) ? Wk : (z == 2) ? Wv : Wo;
  short* dst = Wt + (size_t)z * 1048576;
  const int k0 = blockIdx.x * 64, n0 = blockIdx.y * 64;
  const int t = threadIdx.x;
#pragma unroll
  for (int p = 0; p < 4; ++p) {
    const int r = p * 16 + (t >> 4), c = (t & 15) * 4;
    const float4 wv = *(const float4*)&W[(size_t)(k0 + r) * DMODEL + n0 + c];
    T[c + 0][r] = f2bf(wv.x);
    T[c + 1][r] = f2bf(wv.y);
    T[c + 2][r] = f2bf(wv.z);
    T[c + 3][r] = f2bf(wv.w);
  }
  __syncthreads();
  const int rr = t >> 2, cc = (t & 3) * 16;
  const bf16x8 x0 = *(const bf16x8*)&T[rr][cc];
  const bf16x8 x1 = *(const bf16x8*)&T[rr][cc + 8];
  short* d = dst + (size_t)(n0 + rr) * DMODEL + k0 + cc;
  *(bf16x8*)&d[0] = x0;
  *(bf16x8*)&d[8] = x1;
}

// ---------------------------------------------------------------------------
// Bf16 tile staging with bank-conflict-free XOR chunk swizzle.
// Tile [128][32] bf16 (64 B rows, 4 chunks of 16 B). Chunk c of row r lives
// at slot c ^ ((r>>1)&3). Frag read for k-chunk quad: slot quad^((l15>>1)&3).
// Banks: base = (l15&1)*16 + slot*4 -> 2 lanes per bank-quad = conflict-free.
// ---------------------------------------------------------------------------
__device__ __forceinline__ void stage_tile32(const short* gbase, short (*tile)[32],
                                             int w, int lane) {
  const int row = lane >> 2;                          // 0..15 per issue
  const int g = ((lane & 3) ^ ((row >> 1) & 3)) * 8;  // swizzled global chunk
#pragma unroll
  for (int i = 0; i < 2; ++i) {
    const int r = w * 32 + i * 16 + row;
    gl_lds16(gbase + (size_t)r * DMODEL + g, &tile[w * 32 + i * 16][0]);
  }
}

// ---------------------------------------------------------------------------
// Kernel 1: QKV projection, 128x128 tile, BK=32, all-bf16, swizzled LDS.
// z=0 Q (RoPE+0.125 -> [bh][s][dk]), z=1 K (RoPE), z=2 V^T ([bh][dk][s]).
// ---------------------------------------------------------------------------
__global__ __launch_bounds__(256) void gemm_qkv(
    const short* __restrict__ Xb, const short* __restrict__ Wt,
    const float* __restrict__ bq, const float* __restrict__ bk,
    const float* __restrict__ bv, const float* __restrict__ rope,
    short* __restrict__ Qw, short* __restrict__ Kw, short* __restrict__ Vw) {
  __shared__ char smem[36864];                     // 36 KB (epilogue reuse)
  short (*As)[32] = (short(*)[32])smem;            // 128x32 bf16, 8 KB
  short (*Bs)[32] = (short(*)[32])(smem + 8192);   // 128x32 bf16, 8 KB

  const int z = blockIdx.z;
  const short* X = Xb + (size_t)z * 4194304;
  const float* bias = (z == 0) ? bq : (z == 1) ? bk : bv;
  const short* Wz = Wt + (size_t)z * 1048576;

  const int m0 = blockIdx.x * 128, n0 = blockIdx.y * 128;
  const int t = threadIdx.x;
  const int lane = t & 63;
  const int w = t >> 6;
  const int quad = lane >> 4;
  const int l15 = lane & 15;
  const int wr = (w >> 1) * 64, wc = (w & 1) * 64;
  const int rswz = (quad ^ ((l15 >> 1) & 3)) * 8;  // frag-read swizzled offset

  f32x4 acc[4][4] = {};

  for (int kt = 0; kt < DMODEL; kt += 32) {
    __syncthreads();
    stage_tile32(X + (size_t)m0 * DMODEL + kt, As, w, lane);
    stage_tile32(Wz + (size_t)n0 * DMODEL + kt, Bs, w, lane);
    __syncthreads();
    bf16x8 bf[4], af[4];
#pragma unroll
    for (int nj = 0; nj < 4; ++nj)
      bf[nj] = *(const bf16x8*)&Bs[wc + nj * 16 + l15][rswz];
#pragma unroll
    for (int mi = 0; mi < 4; ++mi)
      af[mi] = *(const bf16x8*)&As[wr + mi * 16 + l15][rswz];
#pragma unroll
    for (int mi = 0; mi < 4; ++mi)
#pragma unroll
      for (int nj = 0; nj < 4; ++nj)
        acc[mi][nj] =
            __builtin_amdgcn_mfma_f32_16x16x32_bf16(af[mi], bf[nj], acc[mi][nj], 0, 0, 0);
  }

  const int b = (m0 + wr) >> 11;
  const int sbase = (m0 + wr) & 2047;

  if (z == 2) {
    __syncthreads();
    short (*tr)[72] = (short(*)[72])(smem + w * 9216);
    const int h = (n0 + wc) >> 6;
#pragma unroll
    for (int nj = 0; nj < 4; ++nj) {
      const float bval = bias[n0 + wc + nj * 16 + l15];
#pragma unroll
      for (int ti = 0; ti < 4; ++ti)
#pragma unroll
        for (int r = 0; r < 4; ++r)
          tr[nj * 16 + l15][ti * 16 + quad * 4 + r] = f2bf(acc[ti][nj][r] + bval);
    }
    asm volatile("s_waitcnt lgkmcnt(0)" ::: "memory");
    const int bh = b * NHEAD + h;
#pragma unroll
    for (int cc = 0; cc < 4; ++cc) {
      const int row = cc * 16 + (lane >> 2);
      const int c0 = (lane & 3) * 16;
      const bf16x8 x0 = *(const bf16x8*)&tr[row][c0];
      const bf16x8 x1 = *(const bf16x8*)&tr[row][c0 + 8];
      short* d = Vw + ((size_t)bh * DKEY + row) * S_LEN + sbase + c0;
      *(bf16x8*)&d[0] = x0;
      *(bf16x8*)&d[8] = x1;
    }
    return;
  }

  short* outw = (z == 0) ? Qw : Kw;
#pragma unroll
  for (int nj = 0; nj < 4; ++nj) {
    const int n = n0 + wc + nj * 16 + l15;
    const float bval = bias[n];
    const int h = n >> 6, dk = n & 63;
    const int bh = b * NHEAD + h;
#pragma unroll
    for (int ti = 0; ti < 4; ++ti) {
#pragma unroll
      for (int r = 0; r < 4; ++r) {
        const int s = sbase + ti * 16 + quad * 4 + r;
        float val = acc[ti][nj][r] + bval;
        const float cosv = rope[((size_t)b * S_LEN + s) * DKEY + (dk | 1)];
        const float sinv = rope[((size_t)b * S_LEN + s) * DKEY + (dk & ~1)];
        const float partner = __shfl_xor(val, 1);
        val = (dk & 1) ? (val * cosv + partner * sinv)
                       : (val * cosv - partner * sinv);
        if (z == 0) val *= 0.125f;
        outw[((size_t)bh * S_LEN + s) * DKEY + dk] = f2bf(val);
      }
    }
  }
}

// ---------------------------------------------------------------------------
// Kernel 2: block-cooperative causal flash attention (unchanged from R5).
// grid (16, 32), 256 thr; block x handles Q-chunks x and 31-x.
// ---------------------------------------------------------------------------
__global__ __launch_bounds__(256) void attn_kernel(
    const short* __restrict__ Qw, const short* __restrict__ Kw,
    const short* __restrict__ Vw, const float* __restrict__ v_mask,
    short* __restrict__ Ow) {
  __shared__ short Kt[2][64][64];
  __shared__ short Vt[2][64][64];
  __shared__ short Sb[4][16][72];

  const int t = threadIdx.x;
  const int w = t >> 6;
  const int lane = t & 63;
  const int quad = lane >> 4;
  const int l15 = lane & 15;
  const int x8 = l15 & 7;
  const int bh = blockIdx.y;
  const int b = bh >> 4;
  const int h = bh & 15;

  const short* Kbase = Kw + (size_t)bh * S_LEN * DKEY;
  const short* Vbase = Vw + (size_t)bh * DKEY * S_LEN;
  const float* vmb = v_mask + (size_t)b * S_LEN;

  const int sRow = lane >> 3;
  const int sCh = (lane & 7) ^ sRow;

  for (int pass = 0; pass < 2; ++pass) {
    const int c = pass ? (31 - (int)blockIdx.x) : (int)blockIdx.x;
    const int qb = c * 64;
    const int qrow = qb + w * 16 + l15;

    const short* Qp = Qw + ((size_t)bh * S_LEN + qrow) * DKEY;
    const bf16x8 q_lo = *(const bf16x8*)(Qp + quad * 8);
    const bf16x8 q_hi = *(const bf16x8*)(Qp + 32 + quad * 8);

    float m_i = -1.0e30f, l_i = 0.f;
    f32x4 acc[4] = {};

    const int niter = c + 1;
    __syncthreads();
#pragma unroll
    for (int i = 0; i < 2; ++i) {
      const int kr = w * 16 + i * 8 + sRow;
      gl_lds16(Kbase + (size_t)kr * DKEY + sCh * 8, &Kt[0][w * 16 + i * 8][0]);
      gl_lds16(Vbase + (size_t)kr * S_LEN + 0 + sCh * 8, &Vt[0][w * 16 + i * 8][0]);
    }
    int cur = 0;
    for (int it = 0; it < niter; ++it) {
      const int j0 = it * 64;
      __syncthreads();
      if (it + 1 < niter) {
        const int jn = j0 + 64;
#pragma unroll
        for (int i = 0; i < 2; ++i) {
          const int kr = w * 16 + i * 8 + sRow;
          gl_lds16(Kbase + (size_t)(jn + kr) * DKEY + sCh * 8,
                   &Kt[cur ^ 1][w * 16 + i * 8][0]);
          gl_lds16(Vbase + (size_t)kr * S_LEN + jn + sCh * 8,
                   &Vt[cur ^ 1][w * 16 + i * 8][0]);
        }
      }
      bf16x8 ka[4][2];
#pragma unroll
      for (int kt = 0; kt < 4; ++kt) {
        ka[kt][0] = *(const bf16x8*)&Kt[cur][kt * 16 + l15][(quad ^ x8) * 8];
        ka[kt][1] = *(const bf16x8*)&Kt[cur][kt * 16 + l15][((4 + quad) ^ x8) * 8];
      }
      f32x4 sv[4];
#pragma unroll
      for (int kt = 0; kt < 4; ++kt) {
        f32x4 s = {};
        s = __builtin_amdgcn_mfma_f32_16x16x32_bf16(ka[kt][0], q_lo, s, 0, 0, 0);
        s = __builtin_amdgcn_mfma_f32_16x16x32_bf16(ka[kt][1], q_hi, s, 0, 0, 0);
        sv[kt] = s;
      }
#pragma unroll
      for (int kt = 0; kt < 4; ++kt) {
        const float4 vm = *(const float4*)&vmb[j0 + kt * 16 + quad * 4];
#pragma unroll
        for (int r = 0; r < 4; ++r) {
          const int kc = j0 + kt * 16 + quad * 4 + r;
          float xv = sv[kt][r] + (vm[r] - 1.0f) * 1.0e12f;
          if (kc > qrow) xv = -1.0e12f;
          sv[kt][r] = xv;
        }
      }
      float mloc = -1.0e30f;
#pragma unroll
      for (int kt = 0; kt < 4; ++kt)
#pragma unroll
        for (int r = 0; r < 4; ++r) mloc = fmaxf(mloc, sv[kt][r]);
      float p[4][4], sl = 0.f;
#pragma unroll
      for (int kt = 0; kt < 4; ++kt)
#pragma unroll
        for (int r = 0; r < 4; ++r) {
          p[kt][r] = __expf(sv[kt][r] - mloc);
          sl += p[kt][r];
        }
      float mt = mloc, st = sl;
#pragma unroll
      for (int off = 16; off <= 32; off <<= 1) {
        const float mo = __shfl_xor(mt, off);
        const float so = __shfl_xor(st, off);
        const float mx = fmaxf(mt, mo);
        st = st * __expf(mt - mx) + so * __expf(mo - mx);
        mt = mx;
      }
      const float mn = fmaxf(m_i, mt);
      const float alpha = __expf(m_i - mn);
      l_i = l_i * alpha + st * __expf(mt - mn);
      m_i = mn;
      const float pscale = __expf(mloc - mn);
#pragma unroll
      for (int dt = 0; dt < 4; ++dt)
#pragma unroll
        for (int r = 0; r < 4; ++r) acc[dt][r] *= alpha;
#pragma unroll
      for (int kt = 0; kt < 4; ++kt) {
        uint2 pw;
        pw.x = pk2bf(p[kt][0] * pscale, p[kt][1] * pscale);
        pw.y = pk2bf(p[kt][2] * pscale, p[kt][3] * pscale);
        *(uint2*)&Sb[w][l15][kt * 16 + quad * 4] = pw;
      }
      asm volatile("s_waitcnt lgkmcnt(0)" ::: "memory");
      const bf16x8 pf0 = *(const bf16x8*)&Sb[w][l15][quad * 8];
      const bf16x8 pf1 = *(const bf16x8*)&Sb[w][l15][32 + quad * 8];
#pragma unroll
      for (int dt = 0; dt < 4; ++dt) {
        const bf16x8 va0 =
            *(const bf16x8*)&Vt[cur][dt * 16 + l15][(quad ^ x8) * 8];
        acc[dt] = __builtin_amdgcn_mfma_f32_16x16x32_bf16(va0, pf0, acc[dt], 0, 0, 0);
        const bf16x8 va1 =
            *(const bf16x8*)&Vt[cur][dt * 16 + l15][((4 + quad) ^ x8) * 8];
        acc[dt] = __builtin_amdgcn_mfma_f32_16x16x32_bf16(va1, pf1, acc[dt], 0, 0, 0);
      }
      cur ^= 1;
    }
#pragma unroll
    for (int dt = 0; dt < 4; ++dt) {
      const float inv = 1.0f / l_i;
      uint2 ov;
      ov.x = pk2bf(acc[dt][0] * inv, acc[dt][1] * inv);
      ov.y = pk2bf(acc[dt][2] * inv, acc[dt][3] * inv);
      *(uint2*)&Sb[w][l15][dt * 16 + quad * 4] = ov;
    }
    asm volatile("s_waitcnt lgkmcnt(0)" ::: "memory");
    const int qr2 = lane >> 2;
    const int d0 = (lane & 3) * 16;
    const bf16x8 o0 = *(const bf16x8*)&Sb[w][qr2][d0];
    const bf16x8 o1 = *(const bf16x8*)&Sb[w][qr2][d0 + 8];
    short* dst =
        Ow + ((size_t)(b * S_LEN + qb + w * 16 + qr2)) * DMODEL + h * DKEY + d0;
    *(bf16x8*)&dst[0] = o0;
    *(bf16x8*)&dst[8] = o1;
  }
}

// ---------------------------------------------------------------------------
// Kernel 3: output projection, swizzled bf16 tiles. fp32 out + bias.
// ---------------------------------------------------------------------------
__global__ __launch_bounds__(256) void gemm_out(
    const short* __restrict__ A, const short* __restrict__ Wz,
    const float* __restrict__ bias, float* __restrict__ out) {
  __shared__ char smem[16384];
  short (*As)[32] = (short(*)[32])smem;
  short (*Bs)[32] = (short(*)[32])(smem + 8192);

  const int m0 = blockIdx.x * 128, n0 = blockIdx.y * 128;
  const int t = threadIdx.x;
  const int lane = t & 63;
  const int w = t >> 6;
  const int quad = lane >> 4;
  const int l15 = lane & 15;
  const int wr = (w >> 1) * 64, wc = (w & 1) * 64;
  const int rswz = (quad ^ ((l15 >> 1) & 3)) * 8;

  f32x4 acc[4][4] = {};

  for (int kt = 0; kt < DMODEL; kt += 32) {
    __syncthreads();
    stage_tile32(A + (size_t)m0 * DMODEL + kt, As, w, lane);
    stage_tile32(Wz + (size_t)n0 * DMODEL + kt, Bs, w, lane);
    __syncthreads();
    bf16x8 bf[4], af[4];
#pragma unroll
    for (int nj = 0; nj < 4; ++nj)
      bf[nj] = *(const bf16x8*)&Bs[wc + nj * 16 + l15][rswz];
#pragma unroll
    for (int mi = 0; mi < 4; ++mi)
      af[mi] = *(const bf16x8*)&As[wr + mi * 16 + l15][rswz];
#pragma unroll
    for (int mi = 0; mi < 4; ++mi)
#pragma unroll
      for (int nj = 0; nj < 4; ++nj)
        acc[mi][nj] =
            __builtin_amdgcn_mfma_f32_16x16x32_bf16(af[mi], bf[nj], acc[mi][nj], 0, 0, 0);
  }
#pragma unroll
  for (int nj = 0; nj < 4; ++nj) {
    const int n = n0 + wc + nj * 16 + l15;
    const float bval = bias[n];
#pragma unroll
    for (int ti = 0; ti < 4; ++ti)
#pragma unroll
      for (int r = 0; r < 4; ++r) {
        const int m = m0 + wr + ti * 16 + quad * 4 + r;
        out[(size_t)m * DMODEL + n] = acc[ti][nj][r] + bval;
      }
  }
}

// ---------------------------------------------------------------------------
extern "C" void kernel_launch(void* const* d_in, const int* in_sizes, int n_in,
                              void* d_out, int out_size, void* d_ws,
                              size_t ws_size, hipStream_t stream) {
  const float* q      = (const float*)d_in[0];
  const float* k      = (const float*)d_in[1];
  const float* v      = (const float*)d_in[2];
  const float* rope   = (const float*)d_in[3];
  const float* v_mask = (const float*)d_in[5];
  const float* Wq = (const float*)d_in[6];
  const float* bq = (const float*)d_in[7];
  const float* Wk = (const float*)d_in[8];
  const float* bk = (const float*)d_in[9];
  const float* Wv = (const float*)d_in[10];
  const float* bv = (const float*)d_in[11];
  const float* Wo = (const float*)d_in[12];
  const float* bo = (const float*)d_in[13];
  float* out = (float*)d_out;

  short* ws = (short*)d_ws;
  short* Qw = ws;                  // [bh][s][dk] bf16, 8 MB
  short* Kw = ws + 4194304;        // [bh][s][dk] bf16, 8 MB
  short* Vw = ws + 8388608;        // [bh][dk][s] bf16, 8 MB
  short* Ow = ws + 12582912;       // [b][s][dmodel] bf16, 8 MB
  short* Wt = ws + 16777216;       // 4x [n][k] bf16, 8 MB
  short* Xb = ws + 20971520;       // 3x [m][k] bf16, 24 MB  (total 64 MB)

  convert_x<<<dim3(4096, 3), 256, 0, stream>>>(q, k, v, Xb);
  convert_w<<<dim3(16, 16, 4), 256, 0, stream>>>(Wq, Wk, Wv, Wo, Wt);
  gemm_qkv<<<dim3(32, 8, 3), 256, 0, stream>>>(Xb, Wt, bq, bk, bv, rope,
                                               Qw, Kw, Vw);
  attn_kernel<<<dim3(16, 32), 256, 0, stream>>>(Qw, Kw, Vw, v_mask, Ow);
  gemm_out<<<dim3(32, 8), 256, 0, stream>>>(Ow, Wt + 3145728, bo, out);
}